// Round 1
// baseline (257.741 us; speedup 1.0000x reference)
//
#include <hip/hip_runtime.h>
#include <math.h>

// Problem constants (fixed by setup_inputs): B=8, N=M=8192, D=3, fp32.
#define BB 8
#define NN 8192
#define MM 8192
#define BN (BB * NN)   // 65536 query points (pred)
#define BM (BB * MM)   // 65536 target points (tgt)

#define BLOCK 256
#define RROWS 8                    // query rows per thread
#define QB (BLOCK * RROWS)         // 2048 queries per block
#define SPLIT 16                   // m-dimension split across blocks

// Monotone float->int key so signed-int atomicMin orders like float.
__device__ __forceinline__ int enc_key(float v) {
    int b = __float_as_int(v);
    return b >= 0 ? b : (b ^ 0x7fffffff);
}
__device__ __forceinline__ float dec_key(int k) {
    int b = k >= 0 ? k : (k ^ 0x7fffffff);
    return __int_as_float(b);
}

// Pack [*,3] fp32 points into float4 (x, y, z, |p|^2). BN == BM so one grid
// packs both arrays.
__global__ __launch_bounds__(BLOCK) void chamfer_pack(
        const float* __restrict__ pred, const float* __restrict__ tgt,
        float4* __restrict__ pp, float4* __restrict__ pt) {
    int i = blockIdx.x * BLOCK + threadIdx.x;
    if (i < BN) {
        float x = pred[i * 3 + 0], y = pred[i * 3 + 1], z = pred[i * 3 + 2];
        pp[i] = make_float4(x, y, z, fmaf(x, x, fmaf(y, y, z * z)));
    }
    if (i < BM) {
        float x = tgt[i * 3 + 0], y = tgt[i * 3 + 1], z = tgt[i * 3 + 2];
        pt[i] = make_float4(x, y, z, fmaf(x, x, fmaf(y, y, z * z)));
    }
}

// For each query q, compute min over an m-chunk of (|t|^2 - 2 p.t), then
// atomicMin-merge into okeys[q]. Full d^2 = |p|^2 + that value (added in
// finalize). Inner pair cost: 3 v_fma_f32 + 1 v_min_f32.
__global__ __launch_bounds__(BLOCK) void chamfer_minpass(
        const float4* __restrict__ qry, const float4* __restrict__ tgt,
        int* __restrict__ okeys, int nper, int mper) {
    const int qbase = blockIdx.x * QB;
    const int b = qbase / nper;            // block never straddles a batch (QB | N)
    const int t = threadIdx.x;

    float nx[RROWS], ny[RROWS], nz[RROWS], rmin[RROWS];
    #pragma unroll
    for (int r = 0; r < RROWS; ++r) {
        float4 p = qry[qbase + r * BLOCK + t];
        nx[r] = -2.0f * p.x;
        ny[r] = -2.0f * p.y;
        nz[r] = -2.0f * p.z;
        rmin[r] = INFINITY;
    }

    const int mc = mper / SPLIT;
    const float4* __restrict__ tp = tgt + (size_t)b * mper + (size_t)blockIdx.y * mc;

    #pragma unroll 2
    for (int m = 0; m < mc; ++m) {
        float4 tt = tp[m];                 // uniform address -> scalar/broadcast load
        #pragma unroll
        for (int r = 0; r < RROWS; ++r) {
            float v = fmaf(nx[r], tt.x, tt.w);
            v = fmaf(ny[r], tt.y, v);
            v = fmaf(nz[r], tt.z, v);
            rmin[r] = fminf(rmin[r], v);
        }
    }

    #pragma unroll
    for (int r = 0; r < RROWS; ++r)
        atomicMin(&okeys[qbase + r * BLOCK + t], enc_key(rmin[r]));
}

// Per batch: mean_n sqrt(max(d2,0)) and mean_m sqrt(max(d2,0)), then average.
__global__ __launch_bounds__(BLOCK) void chamfer_finalize(
        const int* __restrict__ rk, const int* __restrict__ ck,
        const float4* __restrict__ pp, const float4* __restrict__ pt,
        float* __restrict__ out) {
    const int b = blockIdx.x, t = threadIdx.x;
    float sA = 0.0f, sB = 0.0f;
    for (int n = t; n < NN; n += BLOCK) {
        int i = b * NN + n;
        float d2 = pp[i].w + dec_key(rk[i]);
        sA += sqrtf(fmaxf(d2, 0.0f));
    }
    for (int m = t; m < MM; m += BLOCK) {
        int i = b * MM + m;
        float d2 = pt[i].w + dec_key(ck[i]);
        sB += sqrtf(fmaxf(d2, 0.0f));
    }
    __shared__ float red[BLOCK];
    red[t] = 0.5f * (sA / (float)NN + sB / (float)MM);
    __syncthreads();
    for (int off = BLOCK / 2; off > 0; off >>= 1) {
        if (t < off) red[t] += red[t + off];
        __syncthreads();
    }
    if (t == 0) out[b] = red[0];
}

extern "C" void kernel_launch(void* const* d_in, const int* in_sizes, int n_in,
                              void* d_out, int out_size, void* d_ws, size_t ws_size,
                              hipStream_t stream) {
    const float* pred = (const float*)d_in[0];
    const float* tgtp = (const float*)d_in[1];
    float* out = (float*)d_out;

    // ws layout: packed pred (1 MB) | packed tgt (1 MB) | row keys (256 KB) |
    // col keys (256 KB). Total 2.5 MB.
    char* ws = (char*)d_ws;
    float4* pp = (float4*)ws;
    float4* pt = (float4*)(ws + (size_t)BN * sizeof(float4));
    int* rk = (int*)(ws + (size_t)(BN + BM) * sizeof(float4));
    int* ck = rk + BN;

    // 0x7F7F7F7F decodes to a huge positive float key -> acts as +inf.
    hipMemsetAsync(rk, 0x7F, (size_t)(BN + BM) * sizeof(int), stream);

    chamfer_pack<<<BN / BLOCK, BLOCK, 0, stream>>>(pred, tgtp, pp, pt);

    // pred -> tgt mins (per n), then tgt -> pred mins (per m).
    chamfer_minpass<<<dim3(BN / QB, SPLIT), BLOCK, 0, stream>>>(pp, pt, rk, NN, MM);
    chamfer_minpass<<<dim3(BM / QB, SPLIT), BLOCK, 0, stream>>>(pt, pp, ck, MM, NN);

    chamfer_finalize<<<BB, BLOCK, 0, stream>>>(rk, ck, pp, pt, out);
}

// Round 2
// 179.963 us; speedup vs baseline: 1.4322x; 1.4322x over previous
//
#include <hip/hip_runtime.h>
#include <math.h>

// Problem constants (fixed by setup_inputs): B=8, N=M=8192, D=3, fp32.
#define BB 8
#define NN 8192
#define MM 8192
#define BN (BB * NN)   // 65536 query points (pred)
#define BM (BB * MM)   // 65536 target points (tgt)

#define BLOCK 256
#define RROWS 8                    // query rows per thread
#define QB (BLOCK * RROWS)         // 2048 queries per block
#define SPLIT 64                   // m-dimension split across blocks

#define INF_KEY 0x7F7F7F7F         // decodes to a huge positive float

// Monotone float->int key so signed-int atomicMin orders like float.
__device__ __forceinline__ int enc_key(float v) {
    int b = __float_as_int(v);
    return b >= 0 ? b : (b ^ 0x7fffffff);
}
__device__ __forceinline__ float dec_key(int k) {
    int b = k >= 0 ? k : (k ^ 0x7fffffff);
    return __int_as_float(b);
}

// Pack [*,3] fp32 points into float4 (x, y, z, |p|^2) and init the min-key
// arrays to +inf (replaces a separate hipMemsetAsync dispatch).
__global__ __launch_bounds__(BLOCK) void chamfer_pack(
        const float* __restrict__ pred, const float* __restrict__ tgt,
        float4* __restrict__ pp, float4* __restrict__ pt,
        int* __restrict__ rk, int* __restrict__ ck) {
    int i = blockIdx.x * BLOCK + threadIdx.x;
    {
        float x = pred[i * 3 + 0], y = pred[i * 3 + 1], z = pred[i * 3 + 2];
        pp[i] = make_float4(x, y, z, fmaf(x, x, fmaf(y, y, z * z)));
    }
    {
        float x = tgt[i * 3 + 0], y = tgt[i * 3 + 1], z = tgt[i * 3 + 2];
        pt[i] = make_float4(x, y, z, fmaf(x, x, fmaf(y, y, z * z)));
    }
    rk[i] = INF_KEY;
    ck[i] = INF_KEY;
}

// Both chamfer directions in one dispatch (blockIdx.z selects direction; the
// two passes are symmetric since N == M). For each query q, min over an
// m-chunk of (|t|^2 - 2 p.t), atomicMin-merged into keys[q]. Full d^2 adds
// |q|^2 in finalize. Inner pair cost: 3 v_fma_f32 + 1 v_min_f32.
__global__ __launch_bounds__(BLOCK) void chamfer_minpass(
        const float4* __restrict__ pp, const float4* __restrict__ pt,
        int* __restrict__ rk, int* __restrict__ ck) {
    const bool second = (blockIdx.z != 0);
    const float4* __restrict__ qry = second ? pt : pp;
    const float4* __restrict__ tgt = second ? pp : pt;
    int* __restrict__ okeys = second ? ck : rk;

    const int qbase = blockIdx.x * QB;
    const int b = qbase / NN;              // QB | NN: block never straddles a batch
    const int t = threadIdx.x;

    float nx[RROWS], ny[RROWS], nz[RROWS], rmin[RROWS];
    #pragma unroll
    for (int r = 0; r < RROWS; ++r) {
        float4 p = qry[qbase + r * BLOCK + t];
        nx[r] = -2.0f * p.x;
        ny[r] = -2.0f * p.y;
        nz[r] = -2.0f * p.z;
        rmin[r] = INFINITY;
    }

    const int mc = MM / SPLIT;             // 128
    const float4* __restrict__ tp = tgt + (size_t)b * MM + (size_t)blockIdx.y * mc;

    #pragma unroll 4
    for (int m = 0; m < mc; ++m) {
        float4 tt = tp[m];                 // wave-uniform -> scalar load
        #pragma unroll
        for (int r = 0; r < RROWS; ++r) {
            float v = fmaf(nx[r], tt.x, tt.w);
            v = fmaf(ny[r], tt.y, v);
            v = fmaf(nz[r], tt.z, v);
            rmin[r] = fminf(rmin[r], v);
        }
    }

    #pragma unroll
    for (int r = 0; r < RROWS; ++r)
        atomicMin(&okeys[qbase + r * BLOCK + t], enc_key(rmin[r]));
}

// Per batch: mean_n sqrt(max(d2,0)) and mean_m sqrt(max(d2,0)), then average.
__global__ __launch_bounds__(BLOCK) void chamfer_finalize(
        const int* __restrict__ rk, const int* __restrict__ ck,
        const float4* __restrict__ pp, const float4* __restrict__ pt,
        float* __restrict__ out) {
    const int b = blockIdx.x, t = threadIdx.x;
    float sA = 0.0f, sB = 0.0f;
    for (int n = t; n < NN; n += BLOCK) {
        int i = b * NN + n;
        float d2 = pp[i].w + dec_key(rk[i]);
        sA += sqrtf(fmaxf(d2, 0.0f));
    }
    for (int m = t; m < MM; m += BLOCK) {
        int i = b * MM + m;
        float d2 = pt[i].w + dec_key(ck[i]);
        sB += sqrtf(fmaxf(d2, 0.0f));
    }
    __shared__ float red[BLOCK];
    red[t] = 0.5f * (sA / (float)NN + sB / (float)MM);
    __syncthreads();
    for (int off = BLOCK / 2; off > 0; off >>= 1) {
        if (t < off) red[t] += red[t + off];
        __syncthreads();
    }
    if (t == 0) out[b] = red[0];
}

extern "C" void kernel_launch(void* const* d_in, const int* in_sizes, int n_in,
                              void* d_out, int out_size, void* d_ws, size_t ws_size,
                              hipStream_t stream) {
    const float* pred = (const float*)d_in[0];
    const float* tgtp = (const float*)d_in[1];
    float* out = (float*)d_out;

    // ws layout: packed pred (1 MB) | packed tgt (1 MB) | row keys (256 KB) |
    // col keys (256 KB). Total 2.5 MB.
    char* ws = (char*)d_ws;
    float4* pp = (float4*)ws;
    float4* pt = (float4*)(ws + (size_t)BN * sizeof(float4));
    int* rk = (int*)(ws + (size_t)(BN + BM) * sizeof(float4));
    int* ck = rk + BN;

    chamfer_pack<<<BN / BLOCK, BLOCK, 0, stream>>>(pred, tgtp, pp, pt, rk, ck);

    // Both directions in one dispatch: 32 q-blocks x 64 m-chunks x 2 dirs
    // = 4096 blocks = 16 blocks/CU.
    chamfer_minpass<<<dim3(BN / QB, SPLIT, 2), BLOCK, 0, stream>>>(pp, pt, rk, ck);

    chamfer_finalize<<<BB, BLOCK, 0, stream>>>(rk, ck, pp, pt, out);
}

// Round 3
// 155.839 us; speedup vs baseline: 1.6539x; 1.1548x over previous
//
#include <hip/hip_runtime.h>
#include <math.h>

// Problem constants (fixed by setup_inputs): B=8, N=M=8192, D=3, fp32.
#define BB 8
#define NN 8192
#define MM 8192
#define BN (BB * NN)   // 65536 query points (pred)
#define BM (BB * MM)   // 65536 target points (tgt)

#define BLOCK 256
#define RROWS 8                    // query rows per thread
#define QB (BLOCK * RROWS)         // 2048 queries per block
#define SPLIT 64                   // m-dimension split across blocks

#define INF_KEY 0x7F7F7F7F         // decodes to a huge positive float

// Monotone float->int key so signed-int atomicMin orders like float.
__device__ __forceinline__ int enc_key(float v) {
    int b = __float_as_int(v);
    return b >= 0 ? b : (b ^ 0x7fffffff);
}
__device__ __forceinline__ float dec_key(int k) {
    int b = k >= 0 ? k : (k ^ 0x7fffffff);
    return __int_as_float(b);
}

// Pack [*,3] fp32 points into float4 (x, y, z, |p|^2), init min-key arrays
// to +inf, and zero the output accumulators (finalize atomicAdds into them).
__global__ __launch_bounds__(BLOCK) void chamfer_pack(
        const float* __restrict__ pred, const float* __restrict__ tgt,
        float4* __restrict__ pp, float4* __restrict__ pt,
        int* __restrict__ rk, int* __restrict__ ck,
        float* __restrict__ out) {
    int i = blockIdx.x * BLOCK + threadIdx.x;
    {
        float x = pred[i * 3 + 0], y = pred[i * 3 + 1], z = pred[i * 3 + 2];
        pp[i] = make_float4(x, y, z, fmaf(x, x, fmaf(y, y, z * z)));
    }
    {
        float x = tgt[i * 3 + 0], y = tgt[i * 3 + 1], z = tgt[i * 3 + 2];
        pt[i] = make_float4(x, y, z, fmaf(x, x, fmaf(y, y, z * z)));
    }
    rk[i] = INF_KEY;
    ck[i] = INF_KEY;
    if (blockIdx.x == 0 && threadIdx.x < BB) out[threadIdx.x] = 0.0f;
}

// Both chamfer directions in one dispatch (blockIdx.z selects direction).
// For each query q, min over an m-chunk of (|t|^2 - 2 p.t), atomicMin-merged
// into keys[q]; |q|^2 added in finalize. Inner pair: 3 v_fma + 1 v_min.
// The m-loop is manually software-pipelined (prefetch depth 4) so the
// load->use distance is a full iteration (~260 cyc) > L2 latency.
__global__ __launch_bounds__(BLOCK) void chamfer_minpass(
        const float4* __restrict__ pp, const float4* __restrict__ pt,
        int* __restrict__ rk, int* __restrict__ ck) {
    const bool second = (blockIdx.z != 0);
    const float4* __restrict__ qry = second ? pt : pp;
    const float4* __restrict__ tgt = second ? pp : pt;
    int* __restrict__ okeys = second ? ck : rk;

    const int qbase = blockIdx.x * QB;
    const int b = qbase / NN;              // QB | NN: block never straddles a batch
    const int t = threadIdx.x;

    float nx[RROWS], ny[RROWS], nz[RROWS], rmin[RROWS];
    #pragma unroll
    for (int r = 0; r < RROWS; ++r) {
        float4 p = qry[qbase + r * BLOCK + t];
        nx[r] = -2.0f * p.x;
        ny[r] = -2.0f * p.y;
        nz[r] = -2.0f * p.z;
        rmin[r] = INFINITY;
    }

    const int mc = MM / SPLIT;             // 128
    const float4* __restrict__ tp = tgt + (size_t)b * MM + (size_t)blockIdx.y * mc;

#define PROC(tt)                                          \
    {                                                     \
        _Pragma("unroll")                                 \
        for (int r = 0; r < RROWS; ++r) {                 \
            float v = fmaf(nx[r], (tt).x, (tt).w);        \
            v = fmaf(ny[r], (tt).y, v);                   \
            v = fmaf(nz[r], (tt).z, v);                   \
            rmin[r] = fminf(rmin[r], v);                  \
        }                                                 \
    }

    float4 c0 = tp[0], c1 = tp[1], c2 = tp[2], c3 = tp[3];
    #pragma unroll 1
    for (int m = 0; m + 8 <= mc; m += 4) {
        float4 n0 = tp[m + 4], n1 = tp[m + 5], n2 = tp[m + 6], n3 = tp[m + 7];
        PROC(c0); PROC(c1); PROC(c2); PROC(c3);
        c0 = n0; c1 = n1; c2 = n2; c3 = n3;
    }
    PROC(c0); PROC(c1); PROC(c2); PROC(c3);
#undef PROC

    #pragma unroll
    for (int r = 0; r < RROWS; ++r)
        atomicMin(&okeys[qbase + r * BLOCK + t], enc_key(rmin[r]));
}

// 8 slice-blocks per batch; partial sums atomicAdd'ed into out[b].
#define FSLICE 8
__global__ __launch_bounds__(BLOCK) void chamfer_finalize(
        const int* __restrict__ rk, const int* __restrict__ ck,
        const float4* __restrict__ pp, const float4* __restrict__ pt,
        float* __restrict__ out) {
    const int b = blockIdx.x / FSLICE;
    const int s = blockIdx.x % FSLICE;
    const int t = threadIdx.x;
    const int span = NN / FSLICE;          // 1024
    float sA = 0.0f, sB = 0.0f;
    for (int n = s * span + t; n < (s + 1) * span; n += BLOCK) {
        int i = b * NN + n;
        float d2 = pp[i].w + dec_key(rk[i]);
        sA += sqrtf(fmaxf(d2, 0.0f));
    }
    for (int m = s * span + t; m < (s + 1) * span; m += BLOCK) {
        int i = b * MM + m;
        float d2 = pt[i].w + dec_key(ck[i]);
        sB += sqrtf(fmaxf(d2, 0.0f));
    }
    __shared__ float red[BLOCK];
    red[t] = 0.5f * (sA / (float)NN + sB / (float)MM);
    __syncthreads();
    for (int off = BLOCK / 2; off > 0; off >>= 1) {
        if (t < off) red[t] += red[t + off];
        __syncthreads();
    }
    if (t == 0) atomicAdd(&out[b], red[0]);
}

extern "C" void kernel_launch(void* const* d_in, const int* in_sizes, int n_in,
                              void* d_out, int out_size, void* d_ws, size_t ws_size,
                              hipStream_t stream) {
    const float* pred = (const float*)d_in[0];
    const float* tgtp = (const float*)d_in[1];
    float* out = (float*)d_out;

    // ws layout: packed pred (1 MB) | packed tgt (1 MB) | row keys (256 KB) |
    // col keys (256 KB). Total 2.5 MB.
    char* ws = (char*)d_ws;
    float4* pp = (float4*)ws;
    float4* pt = (float4*)(ws + (size_t)BN * sizeof(float4));
    int* rk = (int*)(ws + (size_t)(BN + BM) * sizeof(float4));
    int* ck = rk + BN;

    chamfer_pack<<<BN / BLOCK, BLOCK, 0, stream>>>(pred, tgtp, pp, pt, rk, ck, out);

    // 32 q-blocks x 64 m-chunks x 2 dirs = 4096 blocks = 16 blocks/CU.
    chamfer_minpass<<<dim3(BN / QB, SPLIT, 2), BLOCK, 0, stream>>>(pp, pt, rk, ck);

    chamfer_finalize<<<BB * FSLICE, BLOCK, 0, stream>>>(rk, ck, pp, pt, out);
}

// Round 4
// 144.475 us; speedup vs baseline: 1.7840x; 1.0787x over previous
//
#include <hip/hip_runtime.h>
#include <math.h>

// Problem constants (fixed by setup_inputs): B=8, N=M=8192, D=3, fp32.
#define BB 8
#define NN 8192
#define MM 8192
#define BN (BB * NN)   // 65536 pred points
#define BM (BB * MM)   // 65536 tgt points
#define NPAIR (BN / 2) // 32768 point-pairs per side

#define BLOCK 256
#define RROWS 8                    // query rows per thread
#define QB (BLOCK * RROWS)         // 2048 queries per block
#define SPLIT 64                   // m-dimension split across blocks

#define INF_KEY 0x7F7F7F7F         // decodes to a huge positive float

typedef float v2f __attribute__((ext_vector_type(2)));

// Monotone float->int key so signed-int atomicMin orders like float.
__device__ __forceinline__ int enc_key(float v) {
    int b = __float_as_int(v);
    return b >= 0 ? b : (b ^ 0x7fffffff);
}
__device__ __forceinline__ float dec_key(int k) {
    int b = k >= 0 ? k : (k ^ 0x7fffffff);
    return __int_as_float(b);
}

// Pack points into PAIR-SoA layout: pair j = points 2j,2j+1 stored as two
// float4s: [x0 x1 y0 y1] [z0 z1 w0 w1], w = |p|^2. This feeds v_pk_fma_f32
// in the minpass with zero shuffle movs. Also inits min-keys and zeroes out.
__global__ __launch_bounds__(BLOCK) void chamfer_pack(
        const float* __restrict__ pred, const float* __restrict__ tgt,
        float4* __restrict__ pp, float4* __restrict__ pt,
        int* __restrict__ rk, int* __restrict__ ck,
        float* __restrict__ out) {
    int j = blockIdx.x * BLOCK + threadIdx.x;      // pair index
    {
        const float* p = pred + (size_t)j * 6;
        float x0 = p[0], y0 = p[1], z0 = p[2], x1 = p[3], y1 = p[4], z1 = p[5];
        float w0 = fmaf(x0, x0, fmaf(y0, y0, z0 * z0));
        float w1 = fmaf(x1, x1, fmaf(y1, y1, z1 * z1));
        pp[j * 2 + 0] = make_float4(x0, x1, y0, y1);
        pp[j * 2 + 1] = make_float4(z0, z1, w0, w1);
    }
    {
        const float* p = tgt + (size_t)j * 6;
        float x0 = p[0], y0 = p[1], z0 = p[2], x1 = p[3], y1 = p[4], z1 = p[5];
        float w0 = fmaf(x0, x0, fmaf(y0, y0, z0 * z0));
        float w1 = fmaf(x1, x1, fmaf(y1, y1, z1 * z1));
        pt[j * 2 + 0] = make_float4(x0, x1, y0, y1);
        pt[j * 2 + 1] = make_float4(z0, z1, w0, w1);
    }
    ((int2*)rk)[j] = make_int2(INF_KEY, INF_KEY);
    ((int2*)ck)[j] = make_int2(INF_KEY, INF_KEY);
    if (blockIdx.x == 0 && threadIdx.x < BB) out[threadIdx.x] = 0.0f;
}

// Both chamfer directions in one dispatch (blockIdx.z). Each thread owns 8
// query rows; streams target PAIRS: per (row, target-pair) the cost is
// 3 v_pk_fma_f32 + 1 v_min3_f32 = 4 issue slots for 2 point-pairs.
__global__ __launch_bounds__(BLOCK) void chamfer_minpass(
        const float4* __restrict__ pp, const float4* __restrict__ pt,
        int* __restrict__ rk, int* __restrict__ ck) {
    const bool second = (blockIdx.z != 0);
    const float4* __restrict__ qry = second ? pt : pp;
    const float4* __restrict__ tgt = second ? pp : pt;
    int* __restrict__ okeys = second ? ck : rk;

    const int qbase = blockIdx.x * QB;
    const int b = qbase / NN;              // QB | NN: block never straddles a batch
    const int t = threadIdx.x;

    v2f nxp[RROWS], nyp[RROWS], nzp[RROWS];
    float rmin[RROWS];
    #pragma unroll
    for (int r = 0; r < RROWS; ++r) {
        int i = qbase + r * BLOCK + t;
        float4 A = qry[(i >> 1) * 2 + 0];  // [x0 x1 y0 y1]
        float4 Bq = qry[(i >> 1) * 2 + 1]; // [z0 z1 w0 w1]
        float x = (i & 1) ? A.y : A.x;
        float y = (i & 1) ? A.w : A.z;
        float z = (i & 1) ? Bq.y : Bq.x;
        nxp[r] = (v2f){-2.0f * x, -2.0f * x};
        nyp[r] = (v2f){-2.0f * y, -2.0f * y};
        nzp[r] = (v2f){-2.0f * z, -2.0f * z};
        rmin[r] = INFINITY;
    }

    const int mc = MM / SPLIT;             // 128 targets = 64 pairs per block
    // Pair p of this chunk lives at tgt[base + 2p], tgt[base + 2p + 1].
    const float4* __restrict__ tp4 = tgt + (size_t)b * MM + (size_t)blockIdx.y * mc;

    #pragma unroll 4
    for (int jp = 0; jp < mc / 2; ++jp) {
        float4 A = tp4[jp * 2 + 0];        // x0 x1 y0 y1
        float4 Bt = tp4[jp * 2 + 1];       // z0 z1 w0 w1
        v2f xx = (v2f){A.x, A.y};
        v2f yy = (v2f){A.z, A.w};
        v2f zz = (v2f){Bt.x, Bt.y};
        v2f ww = (v2f){Bt.z, Bt.w};
        #pragma unroll
        for (int r = 0; r < RROWS; ++r) {
            v2f acc = __builtin_elementwise_fma(nxp[r], xx, ww);
            acc = __builtin_elementwise_fma(nyp[r], yy, acc);
            acc = __builtin_elementwise_fma(nzp[r], zz, acc);
            rmin[r] = fminf(rmin[r], fminf(acc[0], acc[1]));  // v_min3_f32
        }
    }

    #pragma unroll
    for (int r = 0; r < RROWS; ++r)
        atomicMin(&okeys[qbase + r * BLOCK + t], enc_key(rmin[r]));
}

// 8 slice-blocks per batch; partial sums atomicAdd'ed into out[b].
#define FSLICE 8
__global__ __launch_bounds__(BLOCK) void chamfer_finalize(
        const int* __restrict__ rk, const int* __restrict__ ck,
        const float4* __restrict__ pp, const float4* __restrict__ pt,
        float* __restrict__ out) {
    const int b = blockIdx.x / FSLICE;
    const int s = blockIdx.x % FSLICE;
    const int t = threadIdx.x;
    const int span = NN / FSLICE;          // 1024
    const float* ppf = (const float*)pp;
    const float* ptf = (const float*)pt;
    float sA = 0.0f, sB = 0.0f;
    for (int n = s * span + t; n < (s + 1) * span; n += BLOCK) {
        int i = b * NN + n;
        float w = ppf[(size_t)(i >> 1) * 8 + 6 + (i & 1)];
        float d2 = w + dec_key(rk[i]);
        sA += sqrtf(fmaxf(d2, 0.0f));
    }
    for (int m = s * span + t; m < (s + 1) * span; m += BLOCK) {
        int i = b * MM + m;
        float w = ptf[(size_t)(i >> 1) * 8 + 6 + (i & 1)];
        float d2 = w + dec_key(ck[i]);
        sB += sqrtf(fmaxf(d2, 0.0f));
    }
    __shared__ float red[BLOCK];
    red[t] = 0.5f * (sA / (float)NN + sB / (float)MM);
    __syncthreads();
    for (int off = BLOCK / 2; off > 0; off >>= 1) {
        if (t < off) red[t] += red[t + off];
        __syncthreads();
    }
    if (t == 0) atomicAdd(&out[b], red[0]);
}

extern "C" void kernel_launch(void* const* d_in, const int* in_sizes, int n_in,
                              void* d_out, int out_size, void* d_ws, size_t ws_size,
                              hipStream_t stream) {
    const float* pred = (const float*)d_in[0];
    const float* tgtp = (const float*)d_in[1];
    float* out = (float*)d_out;

    // ws layout: packed pred (1 MB) | packed tgt (1 MB) | row keys (256 KB) |
    // col keys (256 KB). Total 2.5 MB.
    char* ws = (char*)d_ws;
    float4* pp = (float4*)ws;
    float4* pt = (float4*)(ws + (size_t)BN * sizeof(float4));
    int* rk = (int*)(ws + (size_t)(BN + BM) * sizeof(float4));
    int* ck = rk + BN;

    chamfer_pack<<<NPAIR / BLOCK, BLOCK, 0, stream>>>(pred, tgtp, pp, pt, rk, ck, out);

    // 32 q-blocks x 64 m-chunks x 2 dirs = 4096 blocks = 16 blocks/CU.
    chamfer_minpass<<<dim3(BN / QB, SPLIT, 2), BLOCK, 0, stream>>>(pp, pt, rk, ck);

    chamfer_finalize<<<BB * FSLICE, BLOCK, 0, stream>>>(rk, ck, pp, pt, out);
}